// Round 5
// baseline (170.587 us; speedup 1.0000x reference)
//
#include <hip/hip_runtime.h>
#include <math.h>

#define NT 16384
#define D 4096
#define NE 128
#define BMT 64            // tokens per block
#define NCH 32            // K-chunks per wave (1024/32)
#define INV_T (1.0f / 0.07f)
#define TAU 3e-6f
#define MARGIN 1e-6f
#define FIXCAP 4096

typedef _Float16 h16;
typedef _Float16 h8 __attribute__((ext_vector_type(8)));
typedef _Float16 h4 __attribute__((ext_vector_type(4)));
typedef float f4 __attribute__((ext_vector_type(4)));

// ---- static device scratch (fully rewritten each call) ----
__device__ float g_wgn[NE * D];          // normalized W fp32 (fixup)
__device__ h16   g_whi[NE * D];          // fp16 hi split [e][k]
__device__ h16   g_wlo[NE * D];          // fp16 lo split
__device__ int   g_tte[NT];
__device__ int   g_cnt;
__device__ int   g_flag[FIXCAP];
__device__ float g_cand[FIXCAP][NE];     // cosine logits of flagged tokens
__device__ float g_me[(NT / BMT) * 4][NE];   // per-wave softmax column sums (1024 rows)
__device__ int   g_hist[NT / 256][NE];
__device__ int   g_pos[NT / 256][NE];

#define GLL(gp, lp) __builtin_amdgcn_global_load_lds( \
    (const __attribute__((address_space(1))) void*)(gp), \
    (__attribute__((address_space(3))) void*)(lp), 16, 0, 0)

// swizzled reduction-buffer address: [half][r][e] fp32, slot^=r kills bank conflicts
#define RADR(H, R, E) ((H) * 32768 + (R) * 512 + (((((E) >> 2) ^ (R)) & 31) << 4) + ((E) & 3) * 4)

// ---------------- kernel 1: normalize W (fp32) + fp16 hi/lo split -------------
__global__ __launch_bounds__(256) void k_prep(const float* __restrict__ wg) {
    int e = blockIdx.x;
    int tid = threadIdx.x;
    if (e == 0 && tid == 0) g_cnt = 0;
    const f4* row = (const f4*)(wg + (size_t)e * D);
    float ss = 0.f;
    f4 v[4];
    #pragma unroll
    for (int c = 0; c < 4; c++) {
        v[c] = row[tid + 256 * c];
        ss += v[c][0]*v[c][0] + v[c][1]*v[c][1] + v[c][2]*v[c][2] + v[c][3]*v[c][3];
    }
    __shared__ float red[4];
    #pragma unroll
    for (int o = 32; o > 0; o >>= 1) ss += __shfl_xor(ss, o, 64);
    if ((tid & 63) == 0) red[tid >> 6] = ss;
    __syncthreads();
    float den = fmaxf(sqrtf(red[0] + red[1] + red[2] + red[3]), 1e-4f);
    #pragma unroll
    for (int c = 0; c < 4; c++) {
        size_t base = (size_t)e * D + (size_t)(tid + 256 * c) * 4;
        f4 wn;
        h4 hi, lo;
        #pragma unroll
        for (int k = 0; k < 4; k++) {
            wn[k] = v[c][k] / den;
            hi[k] = (h16)wn[k];
            lo[k] = (h16)(wn[k] - (float)hi[k]);
        }
        *(f4*)(g_wgn + base) = wn;
        *(h4*)(g_whi + base) = hi;
        *(h4*)(g_wlo + base) = lo;
    }
}

// ---------------- kernel 2: fused fp16x3 MFMA GEMM + epilogue ----------------
// grid 256 (1 block/CU), 256 threads = 4 free-running waves.
// Wave w: 64 tokens x 128 experts over K-quarter [w*1024, w*1024+1024).
// No barriers in the K-loop: private per-wave W buffer + counted vmcnt.
__global__ __launch_bounds__(256, 1) void k_gemm(const float* __restrict__ x) {
    __shared__ __align__(16) char lds[65536];

    const int tid = threadIdx.x;
    const int w = tid >> 6;
    const int l = tid & 63;
    const int lrow = l & 15, lslot = l >> 4;
    const int t0 = blockIdx.x * BMT;

    // x: A-frag direct loads. lane: rows t0 + i*16 + lrow, k = w*1024 + lslot*8
    const float* xb = x + (size_t)(t0 + lrow) * D + w * 1024 + lslot * 8;
    // W staging: lane l -> row q*16 + (l>>2), k-slot (l&3)*8 of this wave's quarter
    const char* srch = (const char*)g_whi + (size_t)(l >> 2) * 8192
                       + (size_t)(l & 3) * 16 + (size_t)w * 2048;
    const char* srcl = (const char*)g_wlo + (size_t)(l >> 2) * 8192
                       + (size_t)(l & 3) * 16 + (size_t)w * 2048;
    char* wb = &lds[w * 16384];   // private: hi 8KB @0, lo 8KB @8192

    f4 xr0[4][2], xr1[4][2];
    f4 acc[4][8];
    #pragma unroll
    for (int i = 0; i < 4; i++)
        #pragma unroll
        for (int j = 0; j < 8; j++) acc[i][j] = (f4)0.0f;
    float ssq[4] = {0.f, 0.f, 0.f, 0.f};
    h8 ah[4], al[4], bh[8], bl[8];

#define STW(c) do { _Pragma("unroll") for (int q = 0; q < 8; q++) { \
        GLL(srch + (size_t)q * 131072 + (size_t)(c) * 64, wb + q * 1024); \
        GLL(srcl + (size_t)q * 131072 + (size_t)(c) * 64, wb + 8192 + q * 1024); } } while (0)

#define LOADX(XS, c) do { _Pragma("unroll") for (int i = 0; i < 4; i++) { \
        XS[i][0] = *(const f4*)(xb + (size_t)i * 65536 + (size_t)(c) * 32); \
        XS[i][1] = *(const f4*)(xb + (size_t)i * 65536 + (size_t)(c) * 32 + 4); } } while (0)

#define CONVX(XS) do { _Pragma("unroll") for (int i = 0; i < 4; i++) { \
        _Pragma("unroll") for (int e = 0; e < 4; e++) { \
            float f0_ = XS[i][0][e], f1_ = XS[i][1][e]; \
            ssq[i] += f0_ * f0_ + f1_ * f1_; \
            h16 h0_ = (h16)f0_, h1_ = (h16)f1_; \
            ah[i][e] = h0_; ah[i][e + 4] = h1_; \
            al[i][e] = (h16)(f0_ - (float)h0_); \
            al[i][e + 4] = (h16)(f1_ - (float)h1_); } } } while (0)

#define DSRD() do { _Pragma("unroll") for (int j = 0; j < 8; j++) { \
        bh[j] = *(const h8*)(wb + (j * 16 + lrow) * 64 + lslot * 16); \
        bl[j] = *(const h8*)(wb + 8192 + (j * 16 + lrow) * 64 + lslot * 16); } } while (0)

#define MFMAS() do { _Pragma("unroll") for (int i = 0; i < 4; i++) \
        _Pragma("unroll") for (int j = 0; j < 8; j++) { \
            acc[i][j] = __builtin_amdgcn_mfma_f32_16x16x32_f16(ah[i], bh[j], acc[i][j], 0, 0, 0); \
            acc[i][j] = __builtin_amdgcn_mfma_f32_16x16x32_f16(ah[i], bl[j], acc[i][j], 0, 0, 0); \
            acc[i][j] = __builtin_amdgcn_mfma_f32_16x16x32_f16(al[i], bh[j], acc[i][j], 0, 0, 0); } } while (0)

// per-chunk: wait own W(c)+x(c) (counted, never drains the pipeline), read W
// frags, convert x, fence LDS reads, restage same buffer, prefetch x, MFMA.
#define CHUNK(C, XS) do { \
        if ((C) + 1 < NCH) asm volatile("s_waitcnt vmcnt(8)" ::: "memory"); \
        else               asm volatile("s_waitcnt vmcnt(0)" ::: "memory"); \
        __builtin_amdgcn_sched_barrier(0); \
        DSRD(); \
        CONVX(XS); \
        asm volatile("s_waitcnt lgkmcnt(0)" ::: "memory"); \
        __builtin_amdgcn_sched_barrier(0); \
        if ((C) + 1 < NCH) STW((C) + 1); \
        if ((C) + 2 < NCH) LOADX(XS, (C) + 2); \
        MFMAS(); \
    } while (0)

    STW(0);
    LOADX(xr0, 0);
    LOADX(xr1, 1);
    #pragma unroll 1
    for (int c = 0; c < NCH; c += 2) {
        CHUNK(c, xr0);
        CHUNK(c + 1, xr1);
    }

    // ================= fused epilogue =================
    __syncthreads();                       // all waves done with their W buffers

    // per-token |x|^2 quarters -> LDS -> regs
    #pragma unroll
    for (int i = 0; i < 4; i++) {
        ssq[i] += __shfl_xor(ssq[i], 16, 64);
        ssq[i] += __shfl_xor(ssq[i], 32, 64);
    }
    float* ssqr = (float*)lds;             // [4][64]
    if (lslot == 0) {
        #pragma unroll
        for (int i = 0; i < 4; i++) ssqr[w * 64 + i * 16 + lrow] = ssq[i];
    }
    __syncthreads();
    const int tl = w * 16 + (l >> 2);      // this lane's epilogue token (local)
    const int e0 = (l & 3) * 32;           // this lane's expert range
    float n2 = ssqr[tl] + ssqr[64 + tl] + ssqr[128 + tl] + ssqr[192 + tl];
    __syncthreads();

#define ACCST(H) do { _Pragma("unroll") for (int i = 0; i < 4; i++) \
        _Pragma("unroll") for (int j = 0; j < 8; j++) \
        _Pragma("unroll") for (int q = 0; q < 4; q++) \
            *(float*)(lds + RADR(H, i * 16 + lslot * 4 + q, j * 16 + lrow)) = acc[i][j][q]; } while (0)

#define ACCADD(H) do { _Pragma("unroll") for (int i = 0; i < 4; i++) \
        _Pragma("unroll") for (int j = 0; j < 8; j++) \
        _Pragma("unroll") for (int q = 0; q < 4; q++) \
            acc[i][j][q] += *(const float*)(lds + RADR(H, i * 16 + lslot * 4 + q, j * 16 + lrow)); } while (0)

    // deterministic cross-wave reduction: (w0+w1) and (w2+w3), then final add
    if (w == 1) ACCST(0);
    if (w == 3) ACCST(1);
    __syncthreads();
    if (w == 0) ACCADD(0);
    if (w == 2) ACCADD(1);
    __syncthreads();
    if (w == 0) ACCST(0);
    if (w == 2) ACCST(1);
    __syncthreads();

    // each lane: token tl, experts [e0, e0+32)
    float v[32];
    #pragma unroll
    for (int k = 0; k < 32; k += 4) {
        f4 a = *(const f4*)(lds + RADR(0, tl, e0 + k));
        f4 b = *(const f4*)(lds + RADR(1, tl, e0 + k));
        v[k]     = a[0] + b[0];
        v[k + 1] = a[1] + b[1];
        v[k + 2] = a[2] + b[2];
        v[k + 3] = a[3] + b[3];
    }

    float scl = 1.0f / fmaxf(sqrtf(n2), 1e-4f);
    float m1 = -1e30f, m2 = -1e30f;
    int a1 = e0;
    #pragma unroll
    for (int k = 0; k < 32; k++) {
        float cv = v[k] * scl;
        v[k] = cv;
        if (cv > m1) { m2 = m1; m1 = cv; a1 = e0 + k; }
        else if (cv > m2) m2 = cv;
    }
    #pragma unroll
    for (int o = 1; o < 4; o <<= 1) {
        float m1o = __shfl_xor(m1, o, 64);
        int   a1o = __shfl_xor(a1, o, 64);
        float m2o = __shfl_xor(m2, o, 64);
        m2 = fmaxf(fmaxf(m2, m2o), fminf(m1, m1o));
        if (m1o > m1 || (m1o == m1 && a1o < a1)) { m1 = m1o; a1 = a1o; }
    }
    const int tg = t0 + tl;
    if ((l & 3) == 0) g_tte[tg] = a1;
    if (m1 - m2 < TAU) {                   // near-tie -> exact recheck later
        int ix = 0;
        if ((l & 3) == 0) ix = atomicAdd(&g_cnt, 1);
        ix = __shfl(ix, l & ~3, 64);
        if (ix < FIXCAP) {
            if ((l & 3) == 0) g_flag[ix] = tg;
            #pragma unroll
            for (int k = 0; k < 32; k += 4) {
                f4 t4;
                t4[0] = v[k]; t4[1] = v[k + 1]; t4[2] = v[k + 2]; t4[3] = v[k + 3];
                *(f4*)&g_cand[ix][e0 + k] = t4;
            }
        }
    }

    // softmax(cos/0.07) -> per-expert column sums over this wave's 16 tokens
    float ssum = 0.f;
    #pragma unroll
    for (int k = 0; k < 32; k++) {
        float ex = __expf((v[k] - m1) * INV_T);
        v[k] = ex;
        ssum += ex;
    }
    ssum += __shfl_xor(ssum, 1, 64);
    ssum += __shfl_xor(ssum, 2, 64);
    float inv = 1.0f / ssum;
    #pragma unroll
    for (int k = 0; k < 32; k++) v[k] *= inv;
    #pragma unroll
    for (int o = 4; o < 64; o <<= 1) {
        #pragma unroll
        for (int k = 0; k < 32; k++) v[k] += __shfl_xor(v[k], o, 64);
    }
    if ((l >> 2) == 0) {
        #pragma unroll
        for (int k = 0; k < 32; k += 4) {
            f4 t4;
            t4[0] = v[k]; t4[1] = v[k + 1]; t4[2] = v[k + 2]; t4[3] = v[k + 3];
            *(f4*)&g_me[blockIdx.x * 4 + w][e0 + k] = t4;
        }
    }

#undef STW
#undef LOADX
#undef CONVX
#undef DSRD
#undef MFMAS
#undef CHUNK
#undef ACCST
#undef ACCADD
}

// ---------------- kernel 3: exact fp32 recheck of near-tie tokens -------------
__global__ __launch_bounds__(64) void k_fix(const float* __restrict__ x) {
    int n = g_cnt;
    if (n > FIXCAP) n = FIXCAP;
    const int l = threadIdx.x;
    for (int i = blockIdx.x; i < n; i += gridDim.x) {
        int t = g_flag[i];
        float c0 = g_cand[i][l], c1 = g_cand[i][l + 64];
        float m = fmaxf(c0, c1);
        #pragma unroll
        for (int o = 1; o < 64; o <<= 1) m = fmaxf(m, __shfl_xor(m, o, 64));
        float thr = m - MARGIN;
        unsigned long long b0 = __ballot(c0 >= thr);
        unsigned long long b1 = __ballot(c1 >= thr);

        const float* xr = x + (size_t)t * D;
        float bm = -1e30f;
        int ba = 0;
        #pragma unroll 1
        for (int half = 0; half < 2; half++) {
            unsigned long long b = half ? b1 : b0;
            while (b) {
                int e = (__ffsll((long long)b) - 1) + half * 64;
                b &= b - 1;
                const float* wr = g_wgn + (size_t)e * D;
                float s = 0.f;
                #pragma unroll 4
                for (int c = 0; c < 16; c++) {
                    f4 xv = *(const f4*)(xr + c * 256 + l * 4);
                    f4 wv = *(const f4*)(wr + c * 256 + l * 4);
                    s = fmaf(xv[0], wv[0], s);
                    s = fmaf(xv[1], wv[1], s);
                    s = fmaf(xv[2], wv[2], s);
                    s = fmaf(xv[3], wv[3], s);
                }
                #pragma unroll
                for (int o = 1; o < 64; o <<= 1) s += __shfl_xor(s, o, 64);
                if (s > bm) { bm = s; ba = e; }   // ascending order + strict > = first-index
            }
        }
        if (l == 0) g_tte[t] = ba;
    }
}

// ---------------- kernel 4: per-chunk expert histograms -----------------------
__global__ __launch_bounds__(256) void k_hist() {
    __shared__ int h[NE];
    int tid = threadIdx.x;
    if (tid < NE) h[tid] = 0;
    __syncthreads();
    atomicAdd(&h[g_tte[blockIdx.x * 256 + tid]], 1);
    __syncthreads();
    if (tid < NE) g_hist[blockIdx.x][tid] = h[tid];
}

// ---------------- kernel 5: scans + l_aux + splits ----------------------------
__global__ __launch_bounds__(128) void k_scan(float* __restrict__ out) {
    __shared__ int total[NE];
    __shared__ float me[NE];
    int e = threadIdx.x;
    int run = 0;
    #pragma unroll 8
    for (int c = 0; c < NT / 256; c++) run += g_hist[c][e];
    total[e] = run;
    __syncthreads();
    int off = 0;
    for (int i = 0; i < e; i++) off += total[i];
    int p = off;
    for (int c = 0; c < NT / 256; c++) { g_pos[c][e] = p; p += g_hist[c][e]; }
    float s = 0.f;
    #pragma unroll 8
    for (int b = 0; b < (NT / BMT) * 4; b++) s += g_me[b][e];
    me[e] = s;
    __syncthreads();
    if (e == 0) {
        float acc = 0.f;
        for (int i = 0; i < NE; i++)
            acc += me[i] * ((float)total[i] * (1.0f / 16384.0f) + 1e-6f);
        out[0] = acc * 128.0f;   // l_aux
    }
    out[1 + NT + e]      = (float)total[e];   // input_splits
    out[1 + NT + NE + e] = (float)total[e];   // output_splits
}

// ---------------- kernel 6: stable placement (counting sort) ------------------
__global__ __launch_bounds__(256) void k_place(float* __restrict__ out) {
    __shared__ int arr[256];
    int tid = threadIdx.x;
    int c = blockIdx.x;
    int t = c * 256 + tid;
    int e = g_tte[t];
    arr[tid] = e;
    __syncthreads();
    int rank = 0;
    for (int j = 0; j < tid; j++) rank += (arr[j] == e) ? 1 : 0;
    out[1 + g_pos[c][e] + rank] = (float)t;
}

// ---------------- launcher ----------------------------------------------------
extern "C" void kernel_launch(void* const* d_in, const int* in_sizes, int n_in,
                              void* d_out, int out_size, void* d_ws, size_t ws_size,
                              hipStream_t stream) {
    const float* x  = (const float*)d_in[0];
    const float* wg = (const float*)d_in[1];
    // d_in[2] = gating_t: sigmoid(x/temp) is monotonic -> argmax unaffected
    float* out = (float*)d_out;

    k_prep<<<NE, 256, 0, stream>>>(wg);
    k_gemm<<<NT / BMT, 256, 0, stream>>>(x);
    k_fix<<<256, 64, 0, stream>>>(x);
    k_hist<<<NT / 256, 256, 0, stream>>>();
    k_scan<<<1, 128, 0, stream>>>(out);
    k_place<<<NT / 256, 256, 0, stream>>>(out);
}

// Round 6
// 140.862 us; speedup vs baseline: 1.2110x; 1.2110x over previous
//
#include <hip/hip_runtime.h>
#include <math.h>

#define NT 16384
#define D 4096
#define NE 128
#define NSPLIT 4
#define KS 1024           // K per slice
#define NCH 32            // chunks per slice (BK=32)
#define BMT 64            // tokens per block
#define INV_T (1.0f / 0.07f)
#define TAU 3e-6f
#define FIXCAP 4096

typedef _Float16 h16;
typedef _Float16 h8 __attribute__((ext_vector_type(8)));
typedef _Float16 h4 __attribute__((ext_vector_type(4)));
typedef float f4 __attribute__((ext_vector_type(4)));

// ---- static device scratch (fully rewritten each call) ----
__device__ float g_S[NSPLIT][NT][NE];    // raw-dot partials (32 MB)
__device__ float g_ssq[NSPLIT][NT];      // |x|^2 partials
__device__ float g_wgn[NE * D];          // normalized W fp32 (fixup)
// W packed chunk-major: [slice][chunk][plane hi/lo][e][4 kslots x 8 h16] -> 16KB per (s,c)
__device__ __align__(16) h16 g_wpk[NE * D * 2];
__device__ int   g_tte[NT];
__device__ int   g_cnt;
__device__ int   g_flag[FIXCAP];
__device__ float g_me[256][NE];
__device__ int   g_hist[256][NE];        // per-64-token-chunk histograms
__device__ int   g_pos[256][NE];

#define GLL(gp, lp) __builtin_amdgcn_global_load_lds( \
    (const __attribute__((address_space(1))) void*)(gp), \
    (__attribute__((address_space(3))) void*)(lp), 16, 0, 0)

// ---------------- kernel 1: normalize W + fp16 hi/lo split + chunk-major pack --
__global__ __launch_bounds__(256) void k_prep(const float* __restrict__ wg) {
    int e = blockIdx.x;
    int tid = threadIdx.x;
    if (e == 0 && tid == 0) g_cnt = 0;
    const f4* row = (const f4*)(wg + (size_t)e * D);
    float ss = 0.f;
    f4 v[4];
    #pragma unroll
    for (int c = 0; c < 4; c++) {
        v[c] = row[tid + 256 * c];
        ss += v[c][0]*v[c][0] + v[c][1]*v[c][1] + v[c][2]*v[c][2] + v[c][3]*v[c][3];
    }
    __shared__ float red[4];
    #pragma unroll
    for (int o = 32; o > 0; o >>= 1) ss += __shfl_xor(ss, o, 64);
    if ((tid & 63) == 0) red[tid >> 6] = ss;
    __syncthreads();
    float den = fmaxf(sqrtf(red[0] + red[1] + red[2] + red[3]), 1e-4f);
    #pragma unroll
    for (int cc = 0; cc < 4; cc++) {
        int k0 = (tid + 256 * cc) * 4;
        f4 wn;
        h4 hi, lo;
        #pragma unroll
        for (int k = 0; k < 4; k++) {
            wn[k] = v[cc][k] / den;
            hi[k] = (h16)wn[k];
            lo[k] = (h16)(wn[k] - (float)hi[k]);
        }
        *(f4*)(g_wgn + (size_t)e * D + k0) = wn;
        // pack: global k -> [s=k>>10][c=(k>>5)&31][p][e][kslot=(k>>3)&3][kk=k&7]
        size_t off = ((size_t)((k0 >> 10) * 32 + ((k0 >> 5) & 31)) * 2) * 8192
                   + (size_t)e * 64 + (size_t)((k0 >> 3) & 3) * 16 + (size_t)(k0 & 7) * 2;
        *(h4*)((char*)g_wpk + off) = hi;
        *(h4*)((char*)g_wpk + off + 8192) = lo;
    }
}

// ---------------- kernel 2: fp16x3 MFMA split-K GEMM --------------------------
// grid 1024 = 256 token-blocks x 4 k-slices -> 4 blocks/CU, 16 waves/CU.
// Block: 4 waves; wave w handles 16 tokens x 128 experts over its slice.
// W: shared 2x16KB LDS double buffer, contiguous global_load_lds staging.
// x: direct global->reg A-fragments, depth-2 prefetch, counted vmcnt(2).
__global__ __launch_bounds__(256, 4) void k_mfma(const float* __restrict__ x) {
    __shared__ __align__(16) char lds[32768];

    const int tid = threadIdx.x;
    const int bid = blockIdx.x;
    const int slice = bid & 3, tb = bid >> 2;
    const int t0 = tb * BMT;
    const int w = tid >> 6, l = tid & 63;
    const int lrow = l & 15, lslot = l >> 4;

    // W staging: chunk (slice,c) is 16KB contiguous; wave stages 4KB x ... 4 GLL of 1KB
    const char* wsrc = (const char*)g_wpk + (size_t)slice * 32 * 16384
                       + (size_t)w * 1024 + (size_t)l * 16;
    // x A-frag: token t0 + w*16 + lrow, k = slice*1024 + c*32 + lslot*8 ..+8
    const float* xb = x + (size_t)(t0 + w * 16 + lrow) * D + slice * KS + lslot * 8;

    f4 acc[8];
    #pragma unroll
    for (int j = 0; j < 8; j++) acc[j] = (f4)0.0f;
    float ssq = 0.f;
    f4 x0[2], x1[2];
    h8 ah, al;

#define STW(buf, c) do { _Pragma("unroll") for (int g = 0; g < 4; g++) \
        GLL(wsrc + (size_t)(c) * 16384 + g * 4096, \
            lds + (buf) * 16384 + g * 4096 + w * 1024); } while (0)

#define LOADX(X, c) do { \
        X[0] = *(const f4*)(xb + (c) * 32); \
        X[1] = *(const f4*)(xb + (c) * 32 + 4); } while (0)

#define CONVX(X) do { _Pragma("unroll") for (int e2 = 0; e2 < 4; e2++) { \
        float f0_ = X[0][e2], f1_ = X[1][e2]; \
        ssq += f0_ * f0_ + f1_ * f1_; \
        h16 h0_ = (h16)f0_, h1_ = (h16)f1_; \
        ah[e2] = h0_; ah[e2 + 4] = h1_; \
        al[e2] = (h16)(f0_ - (float)h0_); \
        al[e2 + 4] = (h16)(f1_ - (float)h1_); } } while (0)

#define MFMAH(buf, j0) do { _Pragma("unroll") for (int j = (j0); j < (j0) + 4; j++) { \
        h8 bhj = *(const h8*)(lds + (buf) * 16384 + (j * 16 + lrow) * 64 + lslot * 16); \
        h8 blj = *(const h8*)(lds + (buf) * 16384 + 8192 + (j * 16 + lrow) * 64 + lslot * 16); \
        acc[j] = __builtin_amdgcn_mfma_f32_16x16x32_f16(ah, bhj, acc[j], 0, 0, 0); \
        acc[j] = __builtin_amdgcn_mfma_f32_16x16x32_f16(ah, blj, acc[j], 0, 0, 0); \
        acc[j] = __builtin_amdgcn_mfma_f32_16x16x32_f16(al, bhj, acc[j], 0, 0, 0); } } while (0)

#define BARR() do { __builtin_amdgcn_sched_barrier(0); \
        __builtin_amdgcn_s_barrier(); \
        __builtin_amdgcn_sched_barrier(0); } while (0)

    // prologue: W(0) + x(0),x(1) in flight; wait W(0)+x(0) (leave x(1): vmcnt 2)
    STW(0, 0);
    LOADX(x0, 0);
    LOADX(x1, 1);
    asm volatile("s_waitcnt vmcnt(2)" ::: "memory");
    BARR();

    #pragma unroll 1
    for (int c = 0; c < NCH; c += 2) {
        // even chunk: buffer 0, regs x0
        STW(1, c + 1);                           // c+1 <= 31 always
        CONVX(x0);
        if (c + 2 < NCH) LOADX(x0, c + 2);
        MFMAH(0, 0); MFMAH(0, 4);
        if (c + 2 < NCH) asm volatile("s_waitcnt vmcnt(2)" ::: "memory");
        else             asm volatile("s_waitcnt vmcnt(0)" ::: "memory");
        BARR();
        // odd chunk: buffer 1, regs x1
        if (c + 2 < NCH) STW(0, c + 2);
        CONVX(x1);
        if (c + 3 < NCH) LOADX(x1, c + 3);
        MFMAH(1, 0); MFMAH(1, 4);
        if (c + 2 < NCH) {
            asm volatile("s_waitcnt vmcnt(2)" ::: "memory");
            BARR();
        }
    }

    // |x|^2 partial: reduce over the 4 k-slot lane groups
    ssq += __shfl_xor(ssq, 16, 64);
    ssq += __shfl_xor(ssq, 32, 64);
    if (lslot == 0) g_ssq[slice][t0 + w * 16 + lrow] = ssq;

    // C write: row = lslot*4 + q, col = j*16 + lrow
    #pragma unroll
    for (int j = 0; j < 8; j++)
        #pragma unroll
        for (int q = 0; q < 4; q++)
            g_S[slice][t0 + w * 16 + lslot * 4 + q][j * 16 + lrow] = acc[j][q];

#undef STW
#undef LOADX
#undef CONVX
#undef MFMAH
#undef BARR
}

// ---------------- kernel 3: epilogue (reduce, argmax, softmax, fused hist) ----
// grid 256 x 128 threads; 64 tokens/block, 2 threads per token
__global__ __launch_bounds__(128) void k_epi() {
    __shared__ float gsm[128][65];
    __shared__ int hh[NE];
    const int tid = threadIdx.x;
    const int t = blockIdx.x * 64 + (tid >> 1);
    const int h = tid & 1;

    hh[tid] = 0;
    if (tid < NE - 128) {}   // NE==128: one write per thread covers all
    __syncthreads();

    float L[64];
    {
        const float* sp = &g_S[0][t][h * 64];
        #pragma unroll
        for (int jj = 0; jj < 16; jj++) {
            f4 v = *(const f4*)(sp + jj * 4);
            L[jj*4+0] = v[0]; L[jj*4+1] = v[1]; L[jj*4+2] = v[2]; L[jj*4+3] = v[3];
        }
    }
    #pragma unroll
    for (int s = 1; s < NSPLIT; s++) {
        const float* sp = &g_S[s][t][h * 64];
        #pragma unroll
        for (int jj = 0; jj < 16; jj++) {
            f4 v = *(const f4*)(sp + jj * 4);
            L[jj*4+0] += v[0]; L[jj*4+1] += v[1]; L[jj*4+2] += v[2]; L[jj*4+3] += v[3];
        }
    }
    float n2 = g_ssq[0][t] + g_ssq[1][t] + g_ssq[2][t] + g_ssq[3][t];
    float scl = 1.0f / fmaxf(sqrtf(n2), 1e-4f);

    float m1 = -1e30f, m2 = -1e30f;
    int a1 = h * 64;
    #pragma unroll
    for (int j = 0; j < 64; j++) {
        float v = L[j] * scl;
        L[j] = v;
        if (v > m1) { m2 = m1; m1 = v; a1 = h * 64 + j; }
        else if (v > m2) m2 = v;
    }
    float m1o = __shfl_xor(m1, 1, 64);
    int   a1o = __shfl_xor(a1, 1, 64);
    float m2o = __shfl_xor(m2, 1, 64);
    float m2g = fmaxf(fmaxf(m2, m2o), fminf(m1, m1o));
    float m1g; int a1g;
    if (m1o > m1 || (m1o == m1 && a1o < a1)) { m1g = m1o; a1g = a1o; }
    else { m1g = m1; a1g = a1; }

    if (h == 0) {
        g_tte[t] = a1g;
        atomicAdd(&hh[a1g], 1);
        if (m1g - m2g < TAU) {               // near-tie -> exact recheck
            int ix = atomicAdd(&g_cnt, 1);
            if (ix < FIXCAP) g_flag[ix] = t;
        }
    }

    float ssum = 0.f;
    #pragma unroll
    for (int j = 0; j < 64; j++) {
        float ex = __expf((L[j] - m1g) * INV_T);
        L[j] = ex;
        ssum += ex;
    }
    ssum += __shfl_xor(ssum, 1, 64);
    float inv = 1.0f / ssum;
    #pragma unroll
    for (int j = 0; j < 64; j++) gsm[tid][j] = L[j] * inv;
    __syncthreads();

    int e = tid;
    int col = e & 63, par = e >> 6;
    float s = 0.f;
    #pragma unroll 8
    for (int m = 0; m < 64; m++) s += gsm[2 * m + par][col];
    g_me[blockIdx.x][e] = s;
    g_hist[blockIdx.x][e] = hh[e];
}

// ---------------- kernel 4: exact fp32 recheck of near-tie tokens -------------
// Candidates = experts within 4*TAU*||x|| of approx max; exact fp32 dots only
// for those, ascending order + strict > = first-index tie-break. Patches hist.
__global__ __launch_bounds__(64) void k_fix(const float* __restrict__ x) {
    int n = g_cnt;
    if (n > FIXCAP) n = FIXCAP;
    const int l = threadIdx.x;
    for (int i = blockIdx.x; i < n; i += gridDim.x) {
        int t = g_flag[i];
        float v0 = g_S[0][t][l], v1 = g_S[0][t][l + 64];
        #pragma unroll
        for (int s = 1; s < NSPLIT; s++) { v0 += g_S[s][t][l]; v1 += g_S[s][t][l + 64]; }
        float m = fmaxf(v0, v1);
        #pragma unroll
        for (int o = 1; o < 64; o <<= 1) m = fmaxf(m, __shfl_xor(m, o, 64));
        float n2 = g_ssq[0][t] + g_ssq[1][t] + g_ssq[2][t] + g_ssq[3][t];
        float thr = m - 4.0f * TAU * fmaxf(sqrtf(n2), 1e-4f);
        unsigned long long b0 = __ballot(v0 >= thr);
        unsigned long long b1 = __ballot(v1 >= thr);

        const float* xr = x + (size_t)t * D;
        float bm = -1e30f;
        int ba = 0;
        #pragma unroll 1
        for (int half = 0; half < 2; half++) {
            unsigned long long b = half ? b1 : b0;
            while (b) {
                int e = (__ffsll((long long)b) - 1) + half * 64;
                b &= b - 1;
                const float* wr = g_wgn + (size_t)e * D;
                float s = 0.f;
                #pragma unroll 4
                for (int c = 0; c < 16; c++) {
                    f4 xv = *(const f4*)(xr + c * 256 + l * 4);
                    f4 wv = *(const f4*)(wr + c * 256 + l * 4);
                    s = fmaf(xv[0], wv[0], s);
                    s = fmaf(xv[1], wv[1], s);
                    s = fmaf(xv[2], wv[2], s);
                    s = fmaf(xv[3], wv[3], s);
                }
                #pragma unroll
                for (int o = 1; o < 64; o <<= 1) s += __shfl_xor(s, o, 64);
                if (s > bm) { bm = s; ba = e; }
            }
        }
        if (l == 0) {
            int old = g_tte[t];
            if (ba != old) {
                g_tte[t] = ba;
                atomicSub(&g_hist[t >> 6][old], 1);
                atomicAdd(&g_hist[t >> 6][ba], 1);
            }
        }
    }
}

// ---------------- kernel 5: scans + l_aux + splits ----------------------------
__global__ __launch_bounds__(128) void k_scan(float* __restrict__ out) {
    __shared__ int total[NE];
    __shared__ float me[NE];
    int e = threadIdx.x;
    int run = 0;
    #pragma unroll 8
    for (int c = 0; c < 256; c++) run += g_hist[c][e];
    total[e] = run;
    __syncthreads();
    int off = 0;
    for (int i = 0; i < e; i++) off += total[i];
    int p = off;
    for (int c = 0; c < 256; c++) { g_pos[c][e] = p; p += g_hist[c][e]; }
    float s = 0.f;
    #pragma unroll 8
    for (int b = 0; b < 256; b++) s += g_me[b][e];
    me[e] = s;
    __syncthreads();
    if (e == 0) {
        float acc = 0.f;
        for (int i = 0; i < NE; i++)
            acc += me[i] * ((float)total[i] * (1.0f / 16384.0f) + 1e-6f);
        out[0] = acc * 128.0f;   // l_aux
    }
    out[1 + NT + e]      = (float)total[e];   // input_splits
    out[1 + NT + NE + e] = (float)total[e];   // output_splits
}

// ---------------- kernel 6: stable placement (counting sort) ------------------
__global__ __launch_bounds__(64) void k_place(float* __restrict__ out) {
    __shared__ int arr[64];
    int tid = threadIdx.x;
    int c = blockIdx.x;
    int t = c * 64 + tid;
    int e = g_tte[t];
    arr[tid] = e;
    __syncthreads();
    int rank = 0;
    for (int j = 0; j < tid; j++) rank += (arr[j] == e) ? 1 : 0;
    out[1 + g_pos[c][e] + rank] = (float)t;
}

// ---------------- launcher ----------------------------------------------------
extern "C" void kernel_launch(void* const* d_in, const int* in_sizes, int n_in,
                              void* d_out, int out_size, void* d_ws, size_t ws_size,
                              hipStream_t stream) {
    const float* x  = (const float*)d_in[0];
    const float* wg = (const float*)d_in[1];
    // d_in[2] = gating_t: sigmoid(x/temp) is monotonic -> argmax unaffected
    float* out = (float*)d_out;

    k_prep<<<NE, 256, 0, stream>>>(wg);
    k_mfma<<<(NT / BMT) * NSPLIT, 256, 0, stream>>>(x);
    k_epi<<<256, 128, 0, stream>>>();
    k_fix<<<256, 64, 0, stream>>>(x);
    k_scan<<<1, 128, 0, stream>>>(out);
    k_place<<<256, 64, 0, stream>>>(out);
}

// Round 7
// 132.273 us; speedup vs baseline: 1.2897x; 1.0649x over previous
//
#include <hip/hip_runtime.h>
#include <math.h>

#define NT 16384
#define D 4096
#define NE 128
#define NSPLIT 4
#define KS 1024           // K per slice
#define NCH 32            // chunks per slice (BK=32)
#define BMT 128           // tokens per block (4 waves x 32)
#define INV_T (1.0f / 0.07f)
#define TAU 3e-6f
#define FIXCAP 4096

typedef _Float16 h16;
typedef _Float16 h8 __attribute__((ext_vector_type(8)));
typedef _Float16 h4 __attribute__((ext_vector_type(4)));
typedef float f4 __attribute__((ext_vector_type(4)));
typedef float f16v __attribute__((ext_vector_type(16)));

// ---- static device scratch (fully rewritten each call) ----
__device__ float g_S[NSPLIT][NT][NE];    // raw-dot partials (32 MB)
__device__ float g_ssq[NSPLIT][NT];      // |x|^2 partials
__device__ float g_wgn[NE * D];          // normalized W fp32 (fixup)
// W packed: [slice][chunk][kh][plane][j][oct][e32][8 h16] -> 16KB per (slice,chunk)
__device__ __align__(16) h16 g_wpk[NE * D * 2];
__device__ int   g_tte[NT];
__device__ int   g_cnt;
__device__ int   g_flag[FIXCAP];
__device__ float g_me[256][NE];
__device__ int   g_hist[256][NE];        // per-64-token-chunk histograms
__device__ int   g_pos[256][NE];

#define GLL(gp, lp) __builtin_amdgcn_global_load_lds( \
    (const __attribute__((address_space(1))) void*)(gp), \
    (__attribute__((address_space(3))) void*)(lp), 16, 0, 0)

// ---------------- kernel 1: normalize W + fp16 hi/lo split + subtile pack -----
__global__ __launch_bounds__(256) void k_prep(const float* __restrict__ wg) {
    int e = blockIdx.x;
    int tid = threadIdx.x;
    if (e == 0 && tid == 0) g_cnt = 0;
    const f4* row = (const f4*)(wg + (size_t)e * D);
    float ss = 0.f;
    f4 v[4];
    #pragma unroll
    for (int c = 0; c < 4; c++) {
        v[c] = row[tid + 256 * c];
        ss += v[c][0]*v[c][0] + v[c][1]*v[c][1] + v[c][2]*v[c][2] + v[c][3]*v[c][3];
    }
    __shared__ float red[4];
    #pragma unroll
    for (int o = 32; o > 0; o >>= 1) ss += __shfl_xor(ss, o, 64);
    if ((tid & 63) == 0) red[tid >> 6] = ss;
    __syncthreads();
    float den = fmaxf(sqrtf(red[0] + red[1] + red[2] + red[3]), 1e-4f);
    #pragma unroll
    for (int cc = 0; cc < 4; cc++) {
        int k0 = (tid + 256 * cc) * 4;
        f4 wn;
        h4 hi, lo;
        #pragma unroll
        for (int k = 0; k < 4; k++) {
            wn[k] = v[cc][k] / den;
            hi[k] = (h16)wn[k];
            lo[k] = (h16)(wn[k] - (float)hi[k]);
        }
        *(f4*)(g_wgn + (size_t)e * D + k0) = wn;
        // pack: k -> slice=k>>10, c=(k>>5)&31, kh=(k>>3)&1, oct=(k>>4)&1, d=k&7
        int slice = k0 >> 10, c = (k0 >> 5) & 31;
        int kh = (k0 >> 3) & 1, oct = (k0 >> 4) & 1, kk = k0 & 7;
        size_t sub = ((((size_t)slice * 32 + c) * 2 + kh) * 2) * 4 + (e >> 5); // p=0
        size_t off = sub * 1024 + (size_t)oct * 512 + (size_t)(e & 31) * 16 + (size_t)kk * 2;
        *(h4*)((char*)g_wpk + off)        = hi;   // hi plane
        *(h4*)((char*)g_wpk + off + 4096) = lo;   // lo plane = +1 subtile group
    }
}

// ---------------- kernel 2: fp16x3 32x32x16 MFMA split-K GEMM -----------------
// grid 512 = 128 token-blocks x 4 slices -> 2 blocks/CU, 8 waves/CU.
// Wave: 32 tokens x 128 experts over its slice (K=1024, 32 chunks of 32).
// W: shared 2x16KB LDS dbuf, contiguous GLL staging; x: global->reg, depth-2.
__global__ __launch_bounds__(256, 2) void k_mfma(const float* __restrict__ x) {
    __shared__ __align__(16) char lds[32768];

    const int tid = threadIdx.x;
    const int bid = blockIdx.x;
    const int slice = bid & 3, tb = bid >> 2;
    const int t0 = tb * BMT;
    const int w = tid >> 6, l = tid & 63;
    const int e5 = l & 31, oct = l >> 5;
    const int rd_off = oct * 512 + e5 * 16;

    const char* wbase = (const char*)g_wpk + (size_t)slice * 32 * 16384;
    // x: row t0 + w*32 + (l&31), k = slice*1024 + oct*16 + [0,16)
    const float* xb = x + (size_t)(t0 + w * 32 + e5) * D + slice * KS + oct * 16;

    f16v acc[4];
    #pragma unroll
    for (int j = 0; j < 4; j++) acc[j] = (f16v)0.0f;
    float ssq = 0.f;
    f4 x0[4], x1[4];
    h8 ah[2], al[2];

#define STW(buf, c) do { \
        const char* s_ = wbase + (size_t)(c) * 16384 + w * 4096 + (size_t)l * 16; \
        char* d_ = lds + (buf) * 16384 + w * 4096; \
        GLL(s_, d_); GLL(s_ + 1024, d_ + 1024); \
        GLL(s_ + 2048, d_ + 2048); GLL(s_ + 3072, d_ + 3072); } while (0)

#define LOADX(X, c) do { \
        X[0] = *(const f4*)(xb + (c) * 32); \
        X[1] = *(const f4*)(xb + (c) * 32 + 4); \
        X[2] = *(const f4*)(xb + (c) * 32 + 8); \
        X[3] = *(const f4*)(xb + (c) * 32 + 12); } while (0)

#define CONVX(X) do { _Pragma("unroll") for (int q = 0; q < 4; q++) { \
        _Pragma("unroll") for (int e2 = 0; e2 < 4; e2++) { \
            float f_ = X[q][e2]; \
            ssq += f_ * f_; \
            h16 h_ = (h16)f_; \
            ah[q >> 1][(q & 1) * 4 + e2] = h_; \
            al[q >> 1][(q & 1) * 4 + e2] = (h16)(f_ - (float)h_); } } } while (0)

#define MFMAC(buf) do { _Pragma("unroll") for (int kh = 0; kh < 2; kh++) { \
        h8 bh[4], bl[4]; \
        _Pragma("unroll") for (int j = 0; j < 4; j++) { \
            bh[j] = *(const h8*)(lds + (buf) * 16384 + ((kh * 2 + 0) * 4 + j) * 1024 + rd_off); \
            bl[j] = *(const h8*)(lds + (buf) * 16384 + ((kh * 2 + 1) * 4 + j) * 1024 + rd_off); } \
        _Pragma("unroll") for (int j = 0; j < 4; j++) { \
            acc[j] = __builtin_amdgcn_mfma_f32_32x32x16_f16(ah[kh], bh[j], acc[j], 0, 0, 0); \
            acc[j] = __builtin_amdgcn_mfma_f32_32x32x16_f16(ah[kh], bl[j], acc[j], 0, 0, 0); \
            acc[j] = __builtin_amdgcn_mfma_f32_32x32x16_f16(al[kh], bh[j], acc[j], 0, 0, 0); } } } while (0)

#define ITER(C, BUF, XS) do { \
        if ((C) + 1 < NCH) STW(1 - (BUF), (C) + 1); \
        CONVX(XS); \
        if ((C) + 2 < NCH) LOADX(XS, (C) + 2); \
        MFMAC(BUF); \
        if ((C) + 1 < NCH) { \
            if ((C) + 2 < NCH) asm volatile("s_waitcnt vmcnt(4)" ::: "memory"); \
            else               asm volatile("s_waitcnt vmcnt(0)" ::: "memory"); \
            __builtin_amdgcn_s_barrier(); \
            __builtin_amdgcn_sched_barrier(0); \
        } } while (0)

    // prologue: W(0) staged first (oldest in FIFO), x(0),x(1) behind it
    STW(0, 0);
    LOADX(x0, 0);
    LOADX(x1, 1);
    asm volatile("s_waitcnt vmcnt(8)" ::: "memory");   // drain W(0), leave x0,x1
    __builtin_amdgcn_s_barrier();
    __builtin_amdgcn_sched_barrier(0);

    #pragma unroll 1
    for (int c = 0; c < NCH; c += 2) {
        ITER(c, 0, x0);
        ITER(c + 1, 1, x1);
    }

    // |x|^2 partial: lane and lane^32 each hold half the k-range
    ssq += __shfl_xor(ssq, 32, 64);
    if (l < 32) g_ssq[slice][t0 + w * 32 + l] = ssq;

    // C write (32x32): row = (q&3)+8*(q>>2)+4*oct, col = j*32 + e5
    #pragma unroll
    for (int j = 0; j < 4; j++)
        #pragma unroll
        for (int q = 0; q < 16; q++) {
            int row = (q & 3) + 8 * (q >> 2) + 4 * oct;
            g_S[slice][t0 + w * 32 + row][j * 32 + e5] = acc[j][q];
        }

#undef STW
#undef LOADX
#undef CONVX
#undef MFMAC
#undef ITER
}

// ---------------- kernel 3: epilogue (reduce, argmax, softmax, fused hist) ----
// grid 256 x 128 threads; 64 tokens/block, 2 threads per token
__global__ __launch_bounds__(128) void k_epi() {
    __shared__ float gsm[128][65];
    __shared__ int hh[NE];
    const int tid = threadIdx.x;
    const int t = blockIdx.x * 64 + (tid >> 1);
    const int h = tid & 1;

    hh[tid] = 0;
    __syncthreads();

    float L[64];
    {
        const float* sp = &g_S[0][t][h * 64];
        #pragma unroll
        for (int jj = 0; jj < 16; jj++) {
            f4 v = *(const f4*)(sp + jj * 4);
            L[jj*4+0] = v[0]; L[jj*4+1] = v[1]; L[jj*4+2] = v[2]; L[jj*4+3] = v[3];
        }
    }
    #pragma unroll
    for (int s = 1; s < NSPLIT; s++) {
        const float* sp = &g_S[s][t][h * 64];
        #pragma unroll
        for (int jj = 0; jj < 16; jj++) {
            f4 v = *(const f4*)(sp + jj * 4);
            L[jj*4+0] += v[0]; L[jj*4+1] += v[1]; L[jj*4+2] += v[2]; L[jj*4+3] += v[3];
        }
    }
    float n2 = g_ssq[0][t] + g_ssq[1][t] + g_ssq[2][t] + g_ssq[3][t];
    float scl = 1.0f / fmaxf(sqrtf(n2), 1e-4f);

    float m1 = -1e30f, m2 = -1e30f;
    int a1 = h * 64;
    #pragma unroll
    for (int j = 0; j < 64; j++) {
        float v = L[j] * scl;
        L[j] = v;
        if (v > m1) { m2 = m1; m1 = v; a1 = h * 64 + j; }
        else if (v > m2) m2 = v;
    }
    float m1o = __shfl_xor(m1, 1, 64);
    int   a1o = __shfl_xor(a1, 1, 64);
    float m2o = __shfl_xor(m2, 1, 64);
    float m2g = fmaxf(fmaxf(m2, m2o), fminf(m1, m1o));
    float m1g; int a1g;
    if (m1o > m1 || (m1o == m1 && a1o < a1)) { m1g = m1o; a1g = a1o; }
    else { m1g = m1; a1g = a1; }

    if (h == 0) {
        g_tte[t] = a1g;
        atomicAdd(&hh[a1g], 1);
        if (m1g - m2g < TAU) {               // near-tie -> exact recheck
            int ix = atomicAdd(&g_cnt, 1);
            if (ix < FIXCAP) g_flag[ix] = t;
        }
    }

    float ssum = 0.f;
    #pragma unroll
    for (int j = 0; j < 64; j++) {
        float ex = __expf((L[j] - m1g) * INV_T);
        L[j] = ex;
        ssum += ex;
    }
    ssum += __shfl_xor(ssum, 1, 64);
    float inv = 1.0f / ssum;
    #pragma unroll
    for (int j = 0; j < 64; j++) gsm[tid][j] = L[j] * inv;
    __syncthreads();

    int e = tid;
    int col = e & 63, par = e >> 6;
    float s = 0.f;
    #pragma unroll 8
    for (int m = 0; m < 64; m++) s += gsm[2 * m + par][col];
    g_me[blockIdx.x][e] = s;
    g_hist[blockIdx.x][e] = hh[e];
}

// ---------------- kernel 4: exact fp32 recheck of near-tie tokens -------------
__global__ __launch_bounds__(64) void k_fix(const float* __restrict__ x) {
    int n = g_cnt;
    if (n > FIXCAP) n = FIXCAP;
    const int l = threadIdx.x;
    for (int i = blockIdx.x; i < n; i += gridDim.x) {
        int t = g_flag[i];
        float v0 = g_S[0][t][l], v1 = g_S[0][t][l + 64];
        #pragma unroll
        for (int s = 1; s < NSPLIT; s++) { v0 += g_S[s][t][l]; v1 += g_S[s][t][l + 64]; }
        float m = fmaxf(v0, v1);
        #pragma unroll
        for (int o = 1; o < 64; o <<= 1) m = fmaxf(m, __shfl_xor(m, o, 64));
        float n2 = g_ssq[0][t] + g_ssq[1][t] + g_ssq[2][t] + g_ssq[3][t];
        float thr = m - 4.0f * TAU * fmaxf(sqrtf(n2), 1e-4f);
        unsigned long long b0 = __ballot(v0 >= thr);
        unsigned long long b1 = __ballot(v1 >= thr);

        const float* xr = x + (size_t)t * D;
        float bm = -1e30f;
        int ba = 0;
        #pragma unroll 1
        for (int half = 0; half < 2; half++) {
            unsigned long long b = half ? b1 : b0;
            while (b) {
                int e = (__ffsll((long long)b) - 1) + half * 64;
                b &= b - 1;
                const float* wr = g_wgn + (size_t)e * D;
                float s = 0.f;
                #pragma unroll 4
                for (int c = 0; c < 16; c++) {
                    f4 xv = *(const f4*)(xr + c * 256 + l * 4);
                    f4 wv = *(const f4*)(wr + c * 256 + l * 4);
                    s = fmaf(xv[0], wv[0], s);
                    s = fmaf(xv[1], wv[1], s);
                    s = fmaf(xv[2], wv[2], s);
                    s = fmaf(xv[3], wv[3], s);
                }
                #pragma unroll
                for (int o = 1; o < 64; o <<= 1) s += __shfl_xor(s, o, 64);
                if (s > bm) { bm = s; ba = e; }   // ascending + strict > = first-index
            }
        }
        if (l == 0) {
            int old = g_tte[t];
            if (ba != old) {
                g_tte[t] = ba;
                atomicSub(&g_hist[t >> 6][old], 1);
                atomicAdd(&g_hist[t >> 6][ba], 1);
            }
        }
    }
}

// ---------------- kernel 5: scans + l_aux + splits ----------------------------
__global__ __launch_bounds__(128) void k_scan(float* __restrict__ out) {
    __shared__ int total[NE];
    __shared__ float me[NE];
    int e = threadIdx.x;
    int run = 0;
    #pragma unroll 8
    for (int c = 0; c < 256; c++) run += g_hist[c][e];
    total[e] = run;
    __syncthreads();
    int off = 0;
    for (int i = 0; i < e; i++) off += total[i];
    int p = off;
    for (int c = 0; c < 256; c++) { g_pos[c][e] = p; p += g_hist[c][e]; }
    float s = 0.f;
    #pragma unroll 8
    for (int b = 0; b < 256; b++) s += g_me[b][e];
    me[e] = s;
    __syncthreads();
    if (e == 0) {
        float acc = 0.f;
        for (int i = 0; i < NE; i++)
            acc += me[i] * ((float)total[i] * (1.0f / 16384.0f) + 1e-6f);
        out[0] = acc * 128.0f;   // l_aux
    }
    out[1 + NT + e]      = (float)total[e];   // input_splits
    out[1 + NT + NE + e] = (float)total[e];   // output_splits
}

// ---------------- kernel 6: stable placement (counting sort) ------------------
__global__ __launch_bounds__(64) void k_place(float* __restrict__ out) {
    __shared__ int arr[64];
    int tid = threadIdx.x;
    int c = blockIdx.x;
    int t = c * 64 + tid;
    int e = g_tte[t];
    arr[tid] = e;
    __syncthreads();
    int rank = 0;
    for (int j = 0; j < tid; j++) rank += (arr[j] == e) ? 1 : 0;
    out[1 + g_pos[c][e] + rank] = (float)t;
}

// ---------------- launcher ----------------------------------------------------
extern "C" void kernel_launch(void* const* d_in, const int* in_sizes, int n_in,
                              void* d_out, int out_size, void* d_ws, size_t ws_size,
                              hipStream_t stream) {
    const float* x  = (const float*)d_in[0];
    const float* wg = (const float*)d_in[1];
    // d_in[2] = gating_t: sigmoid(x/temp) is monotonic -> argmax unaffected
    float* out = (float*)d_out;

    k_prep<<<NE, 256, 0, stream>>>(wg);
    k_mfma<<<(NT / BMT) * NSPLIT, 256, 0, stream>>>(x);
    k_epi<<<256, 128, 0, stream>>>();
    k_fix<<<256, 64, 0, stream>>>(x);
    k_scan<<<1, 128, 0, stream>>>(out);
    k_place<<<256, 64, 0, stream>>>(out);
}